// Round 1
// baseline (3070.179 us; speedup 1.0000x reference)
//
#include <hip/hip_runtime.h>
#include <math.h>

#define NCH 32

// ---------------------------------------------------------------------------
// Pass 1: per-edge y = W1 @ x_s + W2 @ (x_t - x_s); accumulate sum / sumsq
// per channel. Per-thread register accumulators -> wave shuffle reduce ->
// one 64-float partial row per block.
// ---------------------------------------------------------------------------
__global__ __launch_bounds__(256) void k_stats(
    const float* __restrict__ x,
    const int* __restrict__ srci,
    const int* __restrict__ tgti,
    const float* __restrict__ W,       // [32, 64] row-major
    float* __restrict__ partials,      // [gridDim.x, 64]
    int E)
{
    float sum[NCH], ssq[NCH];
#pragma unroll
    for (int c = 0; c < NCH; ++c) { sum[c] = 0.f; ssq[c] = 0.f; }

    const int stride = gridDim.x * blockDim.x;
    for (int e = blockIdx.x * blockDim.x + threadIdx.x; e < E; e += stride) {
        const int s = srci[e];
        const int t = tgti[e];
        const float4* __restrict__ ps = (const float4*)(x + (size_t)s * NCH);
        const float4* __restrict__ pt = (const float4*)(x + (size_t)t * NCH);
        float xs[NCH], dx[NCH];
#pragma unroll
        for (int i = 0; i < NCH / 4; ++i) {
            float4 a = ps[i], b = pt[i];
            xs[4*i+0] = a.x; xs[4*i+1] = a.y; xs[4*i+2] = a.z; xs[4*i+3] = a.w;
            dx[4*i+0] = b.x - a.x; dx[4*i+1] = b.y - a.y;
            dx[4*i+2] = b.z - a.z; dx[4*i+3] = b.w - a.w;
        }
#pragma unroll
        for (int c = 0; c < NCH; ++c) {
            const float* __restrict__ wr = W + c * 64;   // uniform indices -> s_load
            float y = 0.f;
#pragma unroll
            for (int k = 0; k < NCH; ++k) y = fmaf(wr[k], xs[k], y);
#pragma unroll
            for (int k = 0; k < NCH; ++k) y = fmaf(wr[32 + k], dx[k], y);
            sum[c] += y;
            ssq[c] = fmaf(y, y, ssq[c]);
        }
    }

    // 64-lane wave butterfly reduce of all 64 accumulators
#pragma unroll
    for (int c = 0; c < NCH; ++c) {
#pragma unroll
        for (int off = 32; off > 0; off >>= 1) {
            sum[c] += __shfl_down(sum[c], off);
            ssq[c] += __shfl_down(ssq[c], off);
        }
    }

    __shared__ float red[4][64];
    const int lane = threadIdx.x & 63;
    const int wave = threadIdx.x >> 6;
    if (lane == 0) {
#pragma unroll
        for (int c = 0; c < NCH; ++c) {
            red[wave][c]       = sum[c];
            red[wave][NCH + c] = ssq[c];
        }
    }
    __syncthreads();
    if (threadIdx.x < 64) {
        float v = red[0][threadIdx.x] + red[1][threadIdx.x]
                + red[2][threadIdx.x] + red[3][threadIdx.x];
        partials[(size_t)blockIdx.x * 64 + threadIdx.x] = v;
    }
}

// ---------------------------------------------------------------------------
// Reduce block partials, fold BN (training stats, biased var) + gamma/beta
// into per-channel affine: out = a[c]*y + b[c].
// ---------------------------------------------------------------------------
__global__ __launch_bounds__(256) void k_finalize(
    const float* __restrict__ partials, int nblocks,
    const float* __restrict__ gamma, const float* __restrict__ beta,
    float* __restrict__ ab, float invE)
{
    __shared__ float acc[4][64];
    const int v = threadIdx.x & 63;
    const int chunk = threadIdx.x >> 6;
    float s = 0.f;
    for (int b = chunk; b < nblocks; b += 4) s += partials[(size_t)b * 64 + v];
    acc[chunk][v] = s;
    __syncthreads();
    if (threadIdx.x < 64) {
        acc[0][v] = acc[0][v] + acc[1][v] + acc[2][v] + acc[3][v];
    }
    __syncthreads();
    if (threadIdx.x < 32) {
        const int c = threadIdx.x;
        float S = acc[0][c];
        float Q = acc[0][32 + c];
        float mean = S * invE;
        float var  = Q * invE - mean * mean;   // biased var, == mean((y-mean)^2)
        float rstd = rsqrtf(var + 1e-5f);
        float a = gamma[c] * rstd;
        float b = beta[c] - mean * a;
        ab[c]      = a;
        ab[32 + c] = b;
    }
}

// ---------------------------------------------------------------------------
// Pass 2: recompute y, affine (BN) + ELU, scatter-add to out[src].
// ---------------------------------------------------------------------------
__global__ __launch_bounds__(256) void k_apply(
    const float* __restrict__ x,
    const int* __restrict__ srci,
    const int* __restrict__ tgti,
    const float* __restrict__ W,
    const float* __restrict__ ab,
    float* __restrict__ out,
    int E)
{
    const int e = blockIdx.x * 256 + threadIdx.x;
    if (e >= E) return;
    const int s = srci[e];
    const int t = tgti[e];
    const float4* __restrict__ ps = (const float4*)(x + (size_t)s * NCH);
    const float4* __restrict__ pt = (const float4*)(x + (size_t)t * NCH);
    float xs[NCH], dx[NCH];
#pragma unroll
    for (int i = 0; i < NCH / 4; ++i) {
        float4 a = ps[i], b = pt[i];
        xs[4*i+0] = a.x; xs[4*i+1] = a.y; xs[4*i+2] = a.z; xs[4*i+3] = a.w;
        dx[4*i+0] = b.x - a.x; dx[4*i+1] = b.y - a.y;
        dx[4*i+2] = b.z - a.z; dx[4*i+3] = b.w - a.w;
    }
    float* __restrict__ orow = out + (size_t)s * NCH;
#pragma unroll
    for (int c = 0; c < NCH; ++c) {
        const float* __restrict__ wr = W + c * 64;
        float y = 0.f;
#pragma unroll
        for (int k = 0; k < NCH; ++k) y = fmaf(wr[k], xs[k], y);
#pragma unroll
        for (int k = 0; k < NCH; ++k) y = fmaf(wr[32 + k], dx[k], y);
        float v = fmaf(ab[c], y, ab[32 + c]);
        v = (v > 0.f) ? v : (__expf(v) - 1.0f);   // ELU, alpha=1
        atomicAdd(orow + c, v);
    }
}

extern "C" void kernel_launch(void* const* d_in, const int* in_sizes, int n_in,
                              void* d_out, int out_size, void* d_ws, size_t ws_size,
                              hipStream_t stream)
{
    const float* x     = (const float*)d_in[0];
    const int*   ei    = (const int*)d_in[1];     // [2, E] (harness int ABI)
    const float* W     = (const float*)d_in[2];   // [32, 64]
    const float* gamma = (const float*)d_in[3];
    const float* beta  = (const float*)d_in[4];
    const int E = in_sizes[1] / 2;
    const int* srci = ei;
    const int* tgti = ei + E;

    float* ab       = (float*)d_ws;   // 64 floats: a[32], b[32]
    float* partials = ab + 64;        // SB * 64 floats

    const int SB = 512;

    hipMemsetAsync(d_out, 0, (size_t)out_size * sizeof(float), stream);
    k_stats<<<SB, 256, 0, stream>>>(x, srci, tgti, W, partials, E);
    k_finalize<<<1, 256, 0, stream>>>(partials, SB, gamma, beta, ab, 1.0f / (float)E);
    k_apply<<<(E + 255) / 256, 256, 0, stream>>>(x, srci, tgti, W, ab, (float*)d_out, E);
}

// Round 2
// 1128.718 us; speedup vs baseline: 2.7201x; 2.7201x over previous
//
#include <hip/hip_runtime.h>
#include <math.h>

#define NCH 32

// ---------------------------------------------------------------------------
// Pass 1: per-edge y = W1 @ x_s + W2 @ (x_t - x_s); accumulate sum / sumsq per
// channel (block partials). Fused: histogram of src node degrees (int atomics).
// ---------------------------------------------------------------------------
__global__ __launch_bounds__(256) void k_stats_hist(
    const float* __restrict__ x,
    const int* __restrict__ srci,
    const int* __restrict__ tgti,
    const float* __restrict__ W,       // [32, 64] row-major
    float* __restrict__ partials,      // [gridDim.x, 64]
    int* __restrict__ counts,          // [N] or nullptr (fallback path)
    int E)
{
    float sum[NCH], ssq[NCH];
#pragma unroll
    for (int c = 0; c < NCH; ++c) { sum[c] = 0.f; ssq[c] = 0.f; }

    const int stride = gridDim.x * blockDim.x;
    for (int e = blockIdx.x * blockDim.x + threadIdx.x; e < E; e += stride) {
        const int s = srci[e];
        const int t = tgti[e];
        if (counts) atomicAdd(&counts[s], 1);   // degree histogram (no return use)
        const float4* __restrict__ ps = (const float4*)(x + (size_t)s * NCH);
        const float4* __restrict__ pt = (const float4*)(x + (size_t)t * NCH);
        float xs[NCH], dx[NCH];
#pragma unroll
        for (int i = 0; i < NCH / 4; ++i) {
            float4 a = ps[i], b = pt[i];
            xs[4*i+0] = a.x; xs[4*i+1] = a.y; xs[4*i+2] = a.z; xs[4*i+3] = a.w;
            dx[4*i+0] = b.x - a.x; dx[4*i+1] = b.y - a.y;
            dx[4*i+2] = b.z - a.z; dx[4*i+3] = b.w - a.w;
        }
#pragma unroll
        for (int c = 0; c < NCH; ++c) {
            const float* __restrict__ wr = W + c * 64;   // uniform -> s_load
            float y = 0.f;
#pragma unroll
            for (int k = 0; k < NCH; ++k) y = fmaf(wr[k], xs[k], y);
#pragma unroll
            for (int k = 0; k < NCH; ++k) y = fmaf(wr[32 + k], dx[k], y);
            sum[c] += y;
            ssq[c] = fmaf(y, y, ssq[c]);
        }
    }

#pragma unroll
    for (int c = 0; c < NCH; ++c) {
#pragma unroll
        for (int off = 32; off > 0; off >>= 1) {
            sum[c] += __shfl_down(sum[c], off);
            ssq[c] += __shfl_down(ssq[c], off);
        }
    }

    __shared__ float red[4][64];
    const int lane = threadIdx.x & 63;
    const int wave = threadIdx.x >> 6;
    if (lane == 0) {
#pragma unroll
        for (int c = 0; c < NCH; ++c) {
            red[wave][c]       = sum[c];
            red[wave][NCH + c] = ssq[c];
        }
    }
    __syncthreads();
    if (threadIdx.x < 64) {
        float v = red[0][threadIdx.x] + red[1][threadIdx.x]
                + red[2][threadIdx.x] + red[3][threadIdx.x];
        partials[(size_t)blockIdx.x * 64 + threadIdx.x] = v;
    }
}

// ---------------------------------------------------------------------------
// One-block exclusive scan of counts[N] -> offsets[N] (+ cursor copy).
// ---------------------------------------------------------------------------
__global__ __launch_bounds__(256) void k_scan(
    const int* __restrict__ counts,
    int* __restrict__ offsets,
    int* __restrict__ cursor,
    int N)
{
    __shared__ int segsum[256];
    __shared__ int segoff[256];
    const int tid = threadIdx.x;
    const int per = (N + 255) / 256;
    const int lo = tid * per;
    const int hi = min(lo + per, N);
    int s = 0;
    for (int i = lo; i < hi; ++i) s += counts[i];
    segsum[tid] = s;
    __syncthreads();
    if (tid == 0) {
        int acc = 0;
        for (int i = 0; i < 256; ++i) { segoff[i] = acc; acc += segsum[i]; }
    }
    __syncthreads();
    int run = segoff[tid];
    for (int i = lo; i < hi; ++i) {
        offsets[i] = run;
        cursor[i]  = run;
        run += counts[i];
    }
}

// ---------------------------------------------------------------------------
// Scatter tgt ids into per-src-node buckets (CSR payload).
// ---------------------------------------------------------------------------
__global__ __launch_bounds__(256) void k_bucket(
    const int* __restrict__ srci,
    const int* __restrict__ tgti,
    int* __restrict__ cursor,
    int* __restrict__ bucketTgt,
    int E)
{
    const int e = blockIdx.x * 256 + threadIdx.x;
    if (e >= E) return;
    const int s = srci[e];
    const int pos = atomicAdd(&cursor[s], 1);
    bucketTgt[pos] = tgti[e];
}

// ---------------------------------------------------------------------------
// Reduce block partials, fold BN stats + gamma/beta into affine a,b.
// ---------------------------------------------------------------------------
__global__ __launch_bounds__(256) void k_finalize(
    const float* __restrict__ partials, int nblocks,
    const float* __restrict__ gamma, const float* __restrict__ beta,
    float* __restrict__ ab, float invE)
{
    __shared__ float acc[4][64];
    const int v = threadIdx.x & 63;
    const int chunk = threadIdx.x >> 6;
    float s = 0.f;
    for (int b = chunk; b < nblocks; b += 4) s += partials[(size_t)b * 64 + v];
    acc[chunk][v] = s;
    __syncthreads();
    if (threadIdx.x < 64) {
        acc[0][v] = acc[0][v] + acc[1][v] + acc[2][v] + acc[3][v];
    }
    __syncthreads();
    if (threadIdx.x < 32) {
        const int c = threadIdx.x;
        float S = acc[0][c];
        float Q = acc[0][32 + c];
        float mean = S * invE;
        float var  = Q * invE - mean * mean;
        float rstd = rsqrtf(var + 1e-5f);
        float a = gamma[c] * rstd;
        float b = beta[c] - mean * a;
        ab[c]      = a;
        ab[32 + c] = b;
    }
}

// ---------------------------------------------------------------------------
// Pass 2 (CSR): one thread per node. Recompute y for each of the node's
// edges, BN-affine + ELU, accumulate in registers, one 128B store per node.
// Zero float atomics. Also writes zero rows for degree-0 nodes.
// ---------------------------------------------------------------------------
__global__ __launch_bounds__(256) void k_node(
    const float* __restrict__ x,
    const int* __restrict__ bucketTgt,
    const int* __restrict__ offsets,
    const int* __restrict__ counts,
    const float* __restrict__ W,
    const float* __restrict__ ab,
    float* __restrict__ out,
    int N)
{
    const int n = blockIdx.x * 256 + threadIdx.x;
    if (n >= N) return;

    float xs[NCH], acc[NCH];
    const float4* __restrict__ ps = (const float4*)(x + (size_t)n * NCH);
#pragma unroll
    for (int i = 0; i < NCH / 4; ++i) {
        float4 a = ps[i];
        xs[4*i+0] = a.x; xs[4*i+1] = a.y; xs[4*i+2] = a.z; xs[4*i+3] = a.w;
    }
#pragma unroll
    for (int c = 0; c < NCH; ++c) acc[c] = 0.f;

    const int off = offsets[n];
    const int deg = counts[n];
    for (int i = 0; i < deg; ++i) {
        const int t = bucketTgt[off + i];
        const float4* __restrict__ pt = (const float4*)(x + (size_t)t * NCH);
        float dx[NCH];
#pragma unroll
        for (int j = 0; j < NCH / 4; ++j) {
            float4 b = pt[j];
            dx[4*j+0] = b.x - xs[4*j+0]; dx[4*j+1] = b.y - xs[4*j+1];
            dx[4*j+2] = b.z - xs[4*j+2]; dx[4*j+3] = b.w - xs[4*j+3];
        }
#pragma unroll
        for (int c = 0; c < NCH; ++c) {
            const float* __restrict__ wr = W + c * 64;
            float y = 0.f;
#pragma unroll
            for (int k = 0; k < NCH; ++k) y = fmaf(wr[k], xs[k], y);
#pragma unroll
            for (int k = 0; k < NCH; ++k) y = fmaf(wr[32 + k], dx[k], y);
            float v = fmaf(ab[c], y, ab[32 + c]);
            v = (v > 0.f) ? v : (__expf(v) - 1.0f);
            acc[c] += v;
        }
    }

    float4* __restrict__ po = (float4*)(out + (size_t)n * NCH);
#pragma unroll
    for (int i = 0; i < NCH / 4; ++i) {
        float4 w4;
        w4.x = acc[4*i+0]; w4.y = acc[4*i+1]; w4.z = acc[4*i+2]; w4.w = acc[4*i+3];
        po[i] = w4;
    }
}

// ---------------------------------------------------------------------------
// Fallback pass 2 (atomic scatter) if ws_size is too small for CSR.
// ---------------------------------------------------------------------------
__global__ __launch_bounds__(256) void k_apply_atomic(
    const float* __restrict__ x,
    const int* __restrict__ srci,
    const int* __restrict__ tgti,
    const float* __restrict__ W,
    const float* __restrict__ ab,
    float* __restrict__ out,
    int E)
{
    const int e = blockIdx.x * 256 + threadIdx.x;
    if (e >= E) return;
    const int s = srci[e];
    const int t = tgti[e];
    const float4* __restrict__ ps = (const float4*)(x + (size_t)s * NCH);
    const float4* __restrict__ pt = (const float4*)(x + (size_t)t * NCH);
    float xs[NCH], dx[NCH];
#pragma unroll
    for (int i = 0; i < NCH / 4; ++i) {
        float4 a = ps[i], b = pt[i];
        xs[4*i+0] = a.x; xs[4*i+1] = a.y; xs[4*i+2] = a.z; xs[4*i+3] = a.w;
        dx[4*i+0] = b.x - a.x; dx[4*i+1] = b.y - a.y;
        dx[4*i+2] = b.z - a.z; dx[4*i+3] = b.w - a.w;
    }
    float* __restrict__ orow = out + (size_t)s * NCH;
#pragma unroll
    for (int c = 0; c < NCH; ++c) {
        const float* __restrict__ wr = W + c * 64;
        float y = 0.f;
#pragma unroll
        for (int k = 0; k < NCH; ++k) y = fmaf(wr[k], xs[k], y);
#pragma unroll
        for (int k = 0; k < NCH; ++k) y = fmaf(wr[32 + k], dx[k], y);
        float v = fmaf(ab[c], y, ab[32 + c]);
        v = (v > 0.f) ? v : (__expf(v) - 1.0f);
        atomicAdd(orow + c, v);
    }
}

extern "C" void kernel_launch(void* const* d_in, const int* in_sizes, int n_in,
                              void* d_out, int out_size, void* d_ws, size_t ws_size,
                              hipStream_t stream)
{
    const float* x     = (const float*)d_in[0];
    const int*   ei    = (const int*)d_in[1];
    const float* W     = (const float*)d_in[2];
    const float* gamma = (const float*)d_in[3];
    const float* beta  = (const float*)d_in[4];
    const int E = in_sizes[1] / 2;
    const int N = in_sizes[0] / NCH;
    const int* srci = ei;
    const int* tgti = ei + E;

    const int SB = 1024;  // stats grid: 4096 waves -> VGPR-capped ~3 waves/SIMD

    // ws layout (ints then floats, all 4B-aligned)
    size_t need = ((size_t)N + (N + 1) + N + E) * sizeof(int)
                + ((size_t)64 + (size_t)SB * 64) * sizeof(float);

    if (ws_size >= need) {
        int* counts    = (int*)d_ws;
        int* offsets   = counts + N;
        int* cursor    = offsets + N + 1;
        int* bucketTgt = cursor + N;
        float* ab       = (float*)(bucketTgt + E);
        float* partials = ab + 64;

        hipMemsetAsync(counts, 0, (size_t)N * sizeof(int), stream);
        k_stats_hist<<<SB, 256, 0, stream>>>(x, srci, tgti, W, partials, counts, E);
        k_scan<<<1, 256, 0, stream>>>(counts, offsets, cursor, N);
        k_bucket<<<(E + 255) / 256, 256, 0, stream>>>(srci, tgti, cursor, bucketTgt, E);
        k_finalize<<<1, 256, 0, stream>>>(partials, SB, gamma, beta, ab, 1.0f / (float)E);
        k_node<<<(N + 255) / 256, 256, 0, stream>>>(x, bucketTgt, offsets, counts, W, ab,
                                                    (float*)d_out, N);
    } else {
        // fallback: atomic scatter (round-1 path)
        const int SBf = 512;
        float* ab       = (float*)d_ws;
        float* partials = ab + 64;
        hipMemsetAsync(d_out, 0, (size_t)out_size * sizeof(float), stream);
        k_stats_hist<<<SBf, 256, 0, stream>>>(x, srci, tgti, W, partials, nullptr, E);
        k_finalize<<<1, 256, 0, stream>>>(partials, SBf, gamma, beta, ab, 1.0f / (float)E);
        k_apply_atomic<<<(E + 255) / 256, 256, 0, stream>>>(x, srci, tgti, W, ab,
                                                            (float*)d_out, E);
    }
}

// Round 3
// 953.808 us; speedup vs baseline: 3.2189x; 1.1834x over previous
//
#include <hip/hip_runtime.h>
#include <math.h>

#define NCH 32

// ===========================================================================
// FAST PATH: per-node u = (W1-W2)x, v = W2 x;  y_e = u[src] + v[tgt].
//   mean(y)  = (sum_n ds*u + dt*v)/E
//   E[y^2]   = (sum_n ds*u^2 + dt*v^2 + 2*sum_e u[s]v[t])/E
// Per-edge work: 32 FMA (cross term) + 32 FMA (apply) + gathers.
// ===========================================================================

// u,v per node + degree histograms per edge (fused, grid-stride both spaces).
__global__ __launch_bounds__(256) void k_uv_hist(
    const float* __restrict__ x,
    const int* __restrict__ srci, const int* __restrict__ tgti,
    const float* __restrict__ W,        // [32,64] row-major
    float* __restrict__ u, float* __restrict__ v,
    int* __restrict__ cnt_s, int* __restrict__ cnt_t,
    int N, int E)
{
    const int stride = gridDim.x * blockDim.x;
    const int tid0 = blockIdx.x * blockDim.x + threadIdx.x;

    for (int n = tid0; n < N; n += stride) {
        float xs[NCH];
        const float4* __restrict__ ps = (const float4*)(x + (size_t)n * NCH);
#pragma unroll
        for (int i = 0; i < 8; ++i) {
            float4 a = ps[i];
            xs[4*i+0] = a.x; xs[4*i+1] = a.y; xs[4*i+2] = a.z; xs[4*i+3] = a.w;
        }
        float uu[NCH], vv[NCH];
#pragma unroll
        for (int c = 0; c < NCH; ++c) {
            const float* __restrict__ wr = W + c * 64;   // uniform -> s_load
            float su = 0.f, sv = 0.f;
#pragma unroll
            for (int k = 0; k < NCH; ++k) {
                su = fmaf(wr[k] - wr[32 + k], xs[k], su);
                sv = fmaf(wr[32 + k], xs[k], sv);
            }
            uu[c] = su; vv[c] = sv;
        }
        float4* __restrict__ pu = (float4*)(u + (size_t)n * NCH);
        float4* __restrict__ pv = (float4*)(v + (size_t)n * NCH);
#pragma unroll
        for (int i = 0; i < 8; ++i) {
            pu[i] = make_float4(uu[4*i], uu[4*i+1], uu[4*i+2], uu[4*i+3]);
            pv[i] = make_float4(vv[4*i], vv[4*i+1], vv[4*i+2], vv[4*i+3]);
        }
    }

    for (int e = tid0; e < E; e += stride) {
        atomicAdd(&cnt_s[srci[e]], 1);
        atomicAdd(&cnt_t[tgti[e]], 1);
    }
}

// Single-block exclusive scan (1024 threads, wave shuffle scan).
__global__ __launch_bounds__(1024) void k_scan(
    const int* __restrict__ counts,
    int* __restrict__ offsets,
    int* __restrict__ cursor,
    int N)
{
    const int tid = threadIdx.x;
    const int per = (N + 1023) / 1024;
    const int lo = tid * per;
    const int hi = min(lo + per, N);
    int s = 0;
    for (int i = lo; i < hi; ++i) s += counts[i];

    // inclusive wave scan of s
    const int lane = tid & 63, wv = tid >> 6;
    int val = s;
#pragma unroll
    for (int off = 1; off < 64; off <<= 1) {
        int t = __shfl_up(val, off);
        if (lane >= off) val += t;
    }
    __shared__ int wsum[16];
    __shared__ int woff[16];
    if (lane == 63) wsum[wv] = val;
    __syncthreads();
    if (tid == 0) {
        int a = 0;
#pragma unroll
        for (int w = 0; w < 16; ++w) { woff[w] = a; a += wsum[w]; }
    }
    __syncthreads();
    int run = woff[wv] + (val - s);   // exclusive prefix of this thread
    for (int i = lo; i < hi; ++i) {
        offsets[i] = run;
        cursor[i]  = run;
        run += counts[i];
    }
}

// Node-decomposable stats terms: S_c, Qn_c into block partials [blk][64].
__global__ __launch_bounds__(256) void k_node_stats(
    const float* __restrict__ u, const float* __restrict__ v,
    const int* __restrict__ cnt_s, const int* __restrict__ cnt_t,
    float* __restrict__ partials, int N)
{
    float S[NCH], Q[NCH];
#pragma unroll
    for (int c = 0; c < NCH; ++c) { S[c] = 0.f; Q[c] = 0.f; }

    const int stride = gridDim.x * blockDim.x;
    for (int n = blockIdx.x * blockDim.x + threadIdx.x; n < N; n += stride) {
        const float ds = (float)cnt_s[n];
        const float dt = (float)cnt_t[n];
        const float4* __restrict__ pu = (const float4*)(u + (size_t)n * NCH);
        const float4* __restrict__ pv = (const float4*)(v + (size_t)n * NCH);
#pragma unroll
        for (int i = 0; i < 8; ++i) {
            float4 a = pu[i], b = pv[i];
            float ua[4] = {a.x, a.y, a.z, a.w};
            float vb[4] = {b.x, b.y, b.z, b.w};
#pragma unroll
            for (int j = 0; j < 4; ++j) {
                const int c = 4*i + j;
                S[c] = fmaf(ds, ua[j], S[c]);
                S[c] = fmaf(dt, vb[j], S[c]);
                Q[c] = fmaf(ds * ua[j], ua[j], Q[c]);
                Q[c] = fmaf(dt * vb[j], vb[j], Q[c]);
            }
        }
    }

#pragma unroll
    for (int c = 0; c < NCH; ++c) {
#pragma unroll
        for (int off = 32; off > 0; off >>= 1) {
            S[c] += __shfl_down(S[c], off);
            Q[c] += __shfl_down(Q[c], off);
        }
    }
    __shared__ float red[4][64];
    const int lane = threadIdx.x & 63;
    const int wave = threadIdx.x >> 6;
    if (lane == 0) {
#pragma unroll
        for (int c = 0; c < NCH; ++c) { red[wave][c] = S[c]; red[wave][NCH + c] = Q[c]; }
    }
    __syncthreads();
    if (threadIdx.x < 64) {
        partials[(size_t)blockIdx.x * 64 + threadIdx.x] =
            red[0][threadIdx.x] + red[1][threadIdx.x]
          + red[2][threadIdx.x] + red[3][threadIdx.x];
    }
}

// Bucket tgt ids by src (CSR payload) + cross-term sum_e u[s]_c * v[t]_c.
__global__ __launch_bounds__(256) void k_bucket_cross(
    const int* __restrict__ srci, const int* __restrict__ tgti,
    int* __restrict__ cursor, int* __restrict__ bucketTgt,
    const float* __restrict__ u, const float* __restrict__ v,
    float* __restrict__ partials, int E)
{
    float X[NCH];
#pragma unroll
    for (int c = 0; c < NCH; ++c) X[c] = 0.f;

    const int stride = gridDim.x * blockDim.x;
    for (int e = blockIdx.x * blockDim.x + threadIdx.x; e < E; e += stride) {
        const int s = srci[e];
        const int t = tgti[e];
        const int pos = atomicAdd(&cursor[s], 1);
        bucketTgt[pos] = t;
        const float4* __restrict__ pu = (const float4*)(u + (size_t)s * NCH);
        const float4* __restrict__ pv = (const float4*)(v + (size_t)t * NCH);
#pragma unroll
        for (int i = 0; i < 8; ++i) {
            float4 a = pu[i], b = pv[i];
            X[4*i+0] = fmaf(a.x, b.x, X[4*i+0]);
            X[4*i+1] = fmaf(a.y, b.y, X[4*i+1]);
            X[4*i+2] = fmaf(a.z, b.z, X[4*i+2]);
            X[4*i+3] = fmaf(a.w, b.w, X[4*i+3]);
        }
    }

#pragma unroll
    for (int c = 0; c < NCH; ++c) {
#pragma unroll
        for (int off = 32; off > 0; off >>= 1) X[c] += __shfl_down(X[c], off);
    }
    __shared__ float red[4][NCH];
    const int lane = threadIdx.x & 63;
    const int wave = threadIdx.x >> 6;
    if (lane == 0) {
#pragma unroll
        for (int c = 0; c < NCH; ++c) red[wave][c] = X[c];
    }
    __syncthreads();
    if (threadIdx.x < NCH) {
        partials[(size_t)blockIdx.x * NCH + threadIdx.x] =
            red[0][threadIdx.x] + red[1][threadIdx.x]
          + red[2][threadIdx.x] + red[3][threadIdx.x];
    }
}

// Combine partials -> BN affine a,b.
__global__ __launch_bounds__(256) void k_finalize_ab(
    const float* __restrict__ p_ns, int nb_ns,
    const float* __restrict__ p_x, int nb_x,
    const float* __restrict__ gamma, const float* __restrict__ beta,
    float* __restrict__ ab, float invE)
{
    __shared__ float sAcc[4][64];
    __shared__ float xAcc[8][32];
    const int c64 = threadIdx.x & 63, r4 = threadIdx.x >> 6;
    float s = 0.f;
    for (int r = r4; r < nb_ns; r += 4) s += p_ns[(size_t)r * 64 + c64];
    sAcc[r4][c64] = s;
    const int c32 = threadIdx.x & 31, r8 = threadIdx.x >> 5;
    float xx = 0.f;
    for (int r = r8; r < nb_x; r += 8) xx += p_x[(size_t)r * 32 + c32];
    xAcc[r8][c32] = xx;
    __syncthreads();
    if (threadIdx.x < 32) {
        const int c = threadIdx.x;
        float S  = sAcc[0][c] + sAcc[1][c] + sAcc[2][c] + sAcc[3][c];
        float Qn = sAcc[0][32+c] + sAcc[1][32+c] + sAcc[2][32+c] + sAcc[3][32+c];
        float X = 0.f;
#pragma unroll
        for (int r = 0; r < 8; ++r) X += xAcc[r][c];
        float Q = Qn + 2.f * X;
        float mean = S * invE;
        float var  = Q * invE - mean * mean;
        float rstd = rsqrtf(var + 1e-5f);
        float a = gamma[c] * rstd;
        float b = beta[c] - mean * a;
        ab[c] = a; ab[32 + c] = b;
    }
}

// Apply: per src node, y = u[n] + v[t]; affine+ELU; register accumulate;
// one 128B store. Zero rows for degree-0 nodes.
__global__ __launch_bounds__(256) void k_apply_csr(
    const float* __restrict__ u, const float* __restrict__ v,
    const int* __restrict__ bucketTgt, const int* __restrict__ offsets,
    const int* __restrict__ cnt_s,
    const float* __restrict__ ab,
    float* __restrict__ out, int N)
{
    const int n = blockIdx.x * 256 + threadIdx.x;
    if (n >= N) return;

    float uu[NCH], acc[NCH];
    const float4* __restrict__ pu = (const float4*)(u + (size_t)n * NCH);
#pragma unroll
    for (int i = 0; i < 8; ++i) {
        float4 a = pu[i];
        uu[4*i+0] = a.x; uu[4*i+1] = a.y; uu[4*i+2] = a.z; uu[4*i+3] = a.w;
    }
#pragma unroll
    for (int c = 0; c < NCH; ++c) acc[c] = 0.f;

    const int off = offsets[n];
    const int deg = cnt_s[n];
    for (int i = 0; i < deg; ++i) {
        const int t = bucketTgt[off + i];
        const float4* __restrict__ pv = (const float4*)(v + (size_t)t * NCH);
#pragma unroll
        for (int j = 0; j < 8; ++j) {
            float4 b = pv[j];
            float vb[4] = {b.x, b.y, b.z, b.w};
#pragma unroll
            for (int q = 0; q < 4; ++q) {
                const int c = 4*j + q;
                float y = uu[c] + vb[q];
                float z = fmaf(ab[c], y, ab[32 + c]);
                z = (z > 0.f) ? z : (__expf(z) - 1.0f);
                acc[c] += z;
            }
        }
    }

    float4* __restrict__ po = (float4*)(out + (size_t)n * NCH);
#pragma unroll
    for (int i = 0; i < 8; ++i)
        po[i] = make_float4(acc[4*i+0], acc[4*i+1], acc[4*i+2], acc[4*i+3]);
}

// ===========================================================================
// FALLBACK kernels (round-1/2 proven paths, used only if ws too small)
// ===========================================================================
__global__ __launch_bounds__(256) void k_stats_hist(
    const float* __restrict__ x,
    const int* __restrict__ srci, const int* __restrict__ tgti,
    const float* __restrict__ W,
    float* __restrict__ partials, int* __restrict__ counts, int E)
{
    float sum[NCH], ssq[NCH];
#pragma unroll
    for (int c = 0; c < NCH; ++c) { sum[c] = 0.f; ssq[c] = 0.f; }
    const int stride = gridDim.x * blockDim.x;
    for (int e = blockIdx.x * blockDim.x + threadIdx.x; e < E; e += stride) {
        const int s = srci[e];
        const int t = tgti[e];
        if (counts) atomicAdd(&counts[s], 1);
        const float4* ps = (const float4*)(x + (size_t)s * NCH);
        const float4* pt = (const float4*)(x + (size_t)t * NCH);
        float xs[NCH], dx[NCH];
#pragma unroll
        for (int i = 0; i < 8; ++i) {
            float4 a = ps[i], b = pt[i];
            xs[4*i+0] = a.x; xs[4*i+1] = a.y; xs[4*i+2] = a.z; xs[4*i+3] = a.w;
            dx[4*i+0] = b.x - a.x; dx[4*i+1] = b.y - a.y;
            dx[4*i+2] = b.z - a.z; dx[4*i+3] = b.w - a.w;
        }
#pragma unroll
        for (int c = 0; c < NCH; ++c) {
            const float* wr = W + c * 64;
            float y = 0.f;
#pragma unroll
            for (int k = 0; k < NCH; ++k) y = fmaf(wr[k], xs[k], y);
#pragma unroll
            for (int k = 0; k < NCH; ++k) y = fmaf(wr[32 + k], dx[k], y);
            sum[c] += y;
            ssq[c] = fmaf(y, y, ssq[c]);
        }
    }
#pragma unroll
    for (int c = 0; c < NCH; ++c) {
#pragma unroll
        for (int off = 32; off > 0; off >>= 1) {
            sum[c] += __shfl_down(sum[c], off);
            ssq[c] += __shfl_down(ssq[c], off);
        }
    }
    __shared__ float red[4][64];
    const int lane = threadIdx.x & 63, wave = threadIdx.x >> 6;
    if (lane == 0) {
#pragma unroll
        for (int c = 0; c < NCH; ++c) { red[wave][c] = sum[c]; red[wave][NCH+c] = ssq[c]; }
    }
    __syncthreads();
    if (threadIdx.x < 64)
        partials[(size_t)blockIdx.x * 64 + threadIdx.x] =
            red[0][threadIdx.x] + red[1][threadIdx.x] + red[2][threadIdx.x] + red[3][threadIdx.x];
}

__global__ __launch_bounds__(256) void k_finalize(
    const float* __restrict__ partials, int nblocks,
    const float* __restrict__ gamma, const float* __restrict__ beta,
    float* __restrict__ ab, float invE)
{
    __shared__ float acc[4][64];
    const int v = threadIdx.x & 63, chunk = threadIdx.x >> 6;
    float s = 0.f;
    for (int b = chunk; b < nblocks; b += 4) s += partials[(size_t)b * 64 + v];
    acc[chunk][v] = s;
    __syncthreads();
    if (threadIdx.x < 64) acc[0][v] = acc[0][v] + acc[1][v] + acc[2][v] + acc[3][v];
    __syncthreads();
    if (threadIdx.x < 32) {
        const int c = threadIdx.x;
        float mean = acc[0][c] * invE;
        float var  = acc[0][32 + c] * invE - mean * mean;
        float rstd = rsqrtf(var + 1e-5f);
        float a = gamma[c] * rstd;
        ab[c] = a; ab[32 + c] = beta[c] - mean * a;
    }
}

__global__ __launch_bounds__(256) void k_bucket(
    const int* __restrict__ srci, const int* __restrict__ tgti,
    int* __restrict__ cursor, int* __restrict__ bucketTgt, int E)
{
    const int e = blockIdx.x * 256 + threadIdx.x;
    if (e >= E) return;
    const int pos = atomicAdd(&cursor[srci[e]], 1);
    bucketTgt[pos] = tgti[e];
}

__global__ __launch_bounds__(256) void k_node(
    const float* __restrict__ x,
    const int* __restrict__ bucketTgt, const int* __restrict__ offsets,
    const int* __restrict__ counts,
    const float* __restrict__ W, const float* __restrict__ ab,
    float* __restrict__ out, int N)
{
    const int n = blockIdx.x * 256 + threadIdx.x;
    if (n >= N) return;
    float xs[NCH], acc[NCH];
    const float4* ps = (const float4*)(x + (size_t)n * NCH);
#pragma unroll
    for (int i = 0; i < 8; ++i) {
        float4 a = ps[i];
        xs[4*i+0] = a.x; xs[4*i+1] = a.y; xs[4*i+2] = a.z; xs[4*i+3] = a.w;
    }
#pragma unroll
    for (int c = 0; c < NCH; ++c) acc[c] = 0.f;
    const int off = offsets[n], deg = counts[n];
    for (int i = 0; i < deg; ++i) {
        const int t = bucketTgt[off + i];
        const float4* pt = (const float4*)(x + (size_t)t * NCH);
        float dx[NCH];
#pragma unroll
        for (int j = 0; j < 8; ++j) {
            float4 b = pt[j];
            dx[4*j+0] = b.x - xs[4*j+0]; dx[4*j+1] = b.y - xs[4*j+1];
            dx[4*j+2] = b.z - xs[4*j+2]; dx[4*j+3] = b.w - xs[4*j+3];
        }
#pragma unroll
        for (int c = 0; c < NCH; ++c) {
            const float* wr = W + c * 64;
            float y = 0.f;
#pragma unroll
            for (int k = 0; k < NCH; ++k) y = fmaf(wr[k], xs[k], y);
#pragma unroll
            for (int k = 0; k < NCH; ++k) y = fmaf(wr[32 + k], dx[k], y);
            float z = fmaf(ab[c], y, ab[32 + c]);
            z = (z > 0.f) ? z : (__expf(z) - 1.0f);
            acc[c] += z;
        }
    }
    float4* po = (float4*)(out + (size_t)n * NCH);
#pragma unroll
    for (int i = 0; i < 8; ++i)
        po[i] = make_float4(acc[4*i+0], acc[4*i+1], acc[4*i+2], acc[4*i+3]);
}

__global__ __launch_bounds__(256) void k_apply_atomic(
    const float* __restrict__ x,
    const int* __restrict__ srci, const int* __restrict__ tgti,
    const float* __restrict__ W, const float* __restrict__ ab,
    float* __restrict__ out, int E)
{
    const int e = blockIdx.x * 256 + threadIdx.x;
    if (e >= E) return;
    const int s = srci[e], t = tgti[e];
    const float4* ps = (const float4*)(x + (size_t)s * NCH);
    const float4* pt = (const float4*)(x + (size_t)t * NCH);
    float xs[NCH], dx[NCH];
#pragma unroll
    for (int i = 0; i < 8; ++i) {
        float4 a = ps[i], b = pt[i];
        xs[4*i+0] = a.x; xs[4*i+1] = a.y; xs[4*i+2] = a.z; xs[4*i+3] = a.w;
        dx[4*i+0] = b.x - a.x; dx[4*i+1] = b.y - a.y;
        dx[4*i+2] = b.z - a.z; dx[4*i+3] = b.w - a.w;
    }
    float* orow = out + (size_t)s * NCH;
#pragma unroll
    for (int c = 0; c < NCH; ++c) {
        const float* wr = W + c * 64;
        float y = 0.f;
#pragma unroll
        for (int k = 0; k < NCH; ++k) y = fmaf(wr[k], xs[k], y);
#pragma unroll
        for (int k = 0; k < NCH; ++k) y = fmaf(wr[32 + k], dx[k], y);
        float z = fmaf(ab[c], y, ab[32 + c]);
        z = (z > 0.f) ? z : (__expf(z) - 1.0f);
        atomicAdd(orow + c, z);
    }
}

// ===========================================================================
extern "C" void kernel_launch(void* const* d_in, const int* in_sizes, int n_in,
                              void* d_out, int out_size, void* d_ws, size_t ws_size,
                              hipStream_t stream)
{
    const float* x     = (const float*)d_in[0];
    const int*   ei    = (const int*)d_in[1];
    const float* W     = (const float*)d_in[2];
    const float* gamma = (const float*)d_in[3];
    const float* beta  = (const float*)d_in[4];
    const int E = in_sizes[1] / 2;
    const int N = in_sizes[0] / NCH;
    const int* srci = ei;
    const int* tgti = ei + E;

    const int SB = 512;   // grid-stride block count for big kernels

    // full-path ws layout
    size_t need_full = (size_t)(2 * N) * NCH * sizeof(float)            // u, v
                     + ((size_t)4 * N + E) * sizeof(int)                // cnt_s, cnt_t, offsets, cursor, bucketTgt
                     + ((size_t)SB * 64 + (size_t)SB * 32 + 64) * sizeof(float);

    size_t need_csr  = ((size_t)3 * N + E) * sizeof(int)
                     + ((size_t)64 + (size_t)1024 * 64) * sizeof(float);

    if (ws_size >= need_full) {
        float* u        = (float*)d_ws;
        float* v        = u + (size_t)N * NCH;
        int*   cnt_s    = (int*)(v + (size_t)N * NCH);
        int*   cnt_t    = cnt_s + N;
        int*   offsets  = cnt_t + N;
        int*   cursor   = offsets + N;
        int*   bucketTgt= cursor + N;
        float* p_ns     = (float*)(bucketTgt + E);
        float* p_x      = p_ns + (size_t)SB * 64;
        float* ab       = p_x + (size_t)SB * 32;

        hipMemsetAsync(cnt_s, 0, (size_t)(2 * N) * sizeof(int), stream);
        k_uv_hist<<<SB, 256, 0, stream>>>(x, srci, tgti, W, u, v, cnt_s, cnt_t, N, E);
        k_scan<<<1, 1024, 0, stream>>>(cnt_s, offsets, cursor, N);
        k_node_stats<<<SB, 256, 0, stream>>>(u, v, cnt_s, cnt_t, p_ns, N);
        k_bucket_cross<<<SB, 256, 0, stream>>>(srci, tgti, cursor, bucketTgt, u, v, p_x, E);
        k_finalize_ab<<<1, 256, 0, stream>>>(p_ns, SB, p_x, SB, gamma, beta, ab, 1.0f / (float)E);
        k_apply_csr<<<(N + 255) / 256, 256, 0, stream>>>(u, v, bucketTgt, offsets, cnt_s, ab,
                                                         (float*)d_out, N);
    } else if (ws_size >= need_csr) {
        const int SB2 = 1024;
        int* counts    = (int*)d_ws;
        int* offsets   = counts + N;
        int* cursor    = offsets + N;
        int* bucketTgt = cursor + N;
        float* ab       = (float*)(bucketTgt + E);
        float* partials = ab + 64;

        hipMemsetAsync(counts, 0, (size_t)N * sizeof(int), stream);
        k_stats_hist<<<SB2, 256, 0, stream>>>(x, srci, tgti, W, partials, counts, E);
        k_scan<<<1, 1024, 0, stream>>>(counts, offsets, cursor, N);
        k_bucket<<<(E + 255) / 256, 256, 0, stream>>>(srci, tgti, cursor, bucketTgt, E);
        k_finalize<<<1, 256, 0, stream>>>(partials, SB2, gamma, beta, ab, 1.0f / (float)E);
        k_node<<<(N + 255) / 256, 256, 0, stream>>>(x, bucketTgt, offsets, counts, W, ab,
                                                    (float*)d_out, N);
    } else {
        const int SBf = 512;
        float* ab       = (float*)d_ws;
        float* partials = ab + 64;
        hipMemsetAsync(d_out, 0, (size_t)out_size * sizeof(float), stream);
        k_stats_hist<<<SBf, 256, 0, stream>>>(x, srci, tgti, W, partials, nullptr, E);
        k_finalize<<<1, 256, 0, stream>>>(partials, SBf, gamma, beta, ab, 1.0f / (float)E);
        k_apply_atomic<<<(E + 255) / 256, 256, 0, stream>>>(x, srci, tgti, W, ab,
                                                            (float*)d_out, E);
    }
}

// Round 4
// 861.334 us; speedup vs baseline: 3.5644x; 1.1074x over previous
//
#include <hip/hip_runtime.h>
#include <math.h>

#define NCH 32
#define BSH 6                   // nodes per bucket = 64
#define BNODES (1 << BSH)
#define MAXNB 2048              // LDS histogram capacity (N <= 131072)

// ===========================================================================
// FAST PATH:
//   u = (W1-W2) x, v = W2 x per node;  y_e = u[src] + v[tgt]
//   edges bucketed by src>>6 (payload packs src_local<<17 | tgt)
//   stats: direct per-edge sum(y), sum(y^2) with u-rows in LDS
//   apply: per-bucket LDS accumulation, zero global float atomics
// ===========================================================================

// --- per-node u, v ---------------------------------------------------------
__global__ __launch_bounds__(256) void k_uv(
    const float* __restrict__ x, const float* __restrict__ W,
    float* __restrict__ u, float* __restrict__ v, int N)
{
    const int n = blockIdx.x * 256 + threadIdx.x;
    if (n >= N) return;
    float xs[NCH];
    const float4* __restrict__ ps = (const float4*)(x + (size_t)n * NCH);
#pragma unroll
    for (int i = 0; i < 8; ++i) {
        float4 a = ps[i];
        xs[4*i+0] = a.x; xs[4*i+1] = a.y; xs[4*i+2] = a.z; xs[4*i+3] = a.w;
    }
    float4* __restrict__ pu = (float4*)(u + (size_t)n * NCH);
    float4* __restrict__ pv = (float4*)(v + (size_t)n * NCH);
#pragma unroll
    for (int i = 0; i < 8; ++i) {
        float r[8];
#pragma unroll
        for (int j = 0; j < 4; ++j) {
            const int c = 4*i + j;
            const float* __restrict__ wr = W + c * 64;   // uniform -> s_load
            float su = 0.f, sv = 0.f;
#pragma unroll
            for (int k = 0; k < NCH; ++k) {
                su = fmaf(wr[k] - wr[32 + k], xs[k], su);
                sv = fmaf(wr[32 + k], xs[k], sv);
            }
            r[j] = su; r[4 + j] = sv;
        }
        pu[i] = make_float4(r[0], r[1], r[2], r[3]);
        pv[i] = make_float4(r[4], r[5], r[6], r[7]);
    }
}

// --- bucket counts via LDS-privatized histogram ----------------------------
__global__ __launch_bounds__(256) void k_count(
    const int* __restrict__ srci, int* __restrict__ cnt_b, int E, int NB)
{
    __shared__ int h[MAXNB];
    for (int i = threadIdx.x; i < NB; i += 256) h[i] = 0;
    __syncthreads();
    const int stride = gridDim.x * 256;
    for (int e = blockIdx.x * 256 + threadIdx.x; e < E; e += stride)
        atomicAdd(&h[srci[e] >> BSH], 1);
    __syncthreads();
    for (int i = threadIdx.x; i < NB; i += 256)
        if (h[i]) atomicAdd(&cnt_b[i], h[i]);
}

// --- one-block exclusive scan over NB bucket counts ------------------------
__global__ __launch_bounds__(256) void k_scan_b(
    const int* __restrict__ cnt_b, int* __restrict__ off_b,
    int* __restrict__ cur_b, int NB)
{
    __shared__ int segsum[256];
    __shared__ int segoff[256];
    const int tid = threadIdx.x;
    const int per = (NB + 255) / 256;
    const int lo = tid * per;
    const int hi = min(lo + per, NB);
    int s = 0;
    for (int i = lo; i < hi; ++i) s += cnt_b[i];
    segsum[tid] = s;
    __syncthreads();
    if (tid == 0) {
        int a = 0;
        for (int i = 0; i < 256; ++i) { segoff[i] = a; a += segsum[i]; }
    }
    __syncthreads();
    int run = segoff[tid];
    for (int i = lo; i < hi; ++i) {
        off_b[i] = run;
        cur_b[i] = run;
        run += cnt_b[i];
    }
}

// --- scatter edges into buckets: payload = (src&63)<<17 | tgt --------------
__global__ __launch_bounds__(256) void k_bucket2(
    const int* __restrict__ srci, const int* __restrict__ tgti,
    int* __restrict__ cur_b, int* __restrict__ payload, int E)
{
    const int e = blockIdx.x * 256 + threadIdx.x;
    if (e >= E) return;
    const int s = srci[e];
    const int b = s >> BSH;
    const int pos = atomicAdd(&cur_b[b], 1);
    payload[pos] = ((s & (BNODES - 1)) << 17) | tgti[e];
}

// --- per-bucket stats: sum(y), sum(y^2) ------------------------------------
__global__ __launch_bounds__(256) void k_stats_b(
    const float* __restrict__ u, const float* __restrict__ v,
    const int* __restrict__ payload, const int* __restrict__ off_b,
    const int* __restrict__ cnt_b,
    float* __restrict__ partials, int N)
{
    __shared__ float uL[BNODES * NCH];
    __shared__ float red[2][256];
    const int b = blockIdx.x;
    const int base = (b << BSH) * NCH;
    const int lim = N * NCH;
    for (int i = threadIdx.x; i < BNODES * NCH; i += 256) {
        const int gi = base + i;
        uL[i] = (gi < lim) ? u[gi] : 0.f;
    }
    __syncthreads();

    const int off = off_b[b];
    const int cnt = cnt_b[b];
    const int g = threadIdx.x >> 5;     // edge sub-lane 0..7
    const int c = threadIdx.x & 31;     // channel
    float sum = 0.f, ssq = 0.f;
    for (int i = g; i < cnt; i += 8) {
        const int w = payload[off + i];      // broadcast within group
        const int t = w & 0x1FFFF;
        const int sl = w >> 17;
        const float y = uL[(sl << 5) + c] + v[(size_t)t * NCH + c];
        sum += y;
        ssq = fmaf(y, y, ssq);
    }
    red[0][threadIdx.x] = sum;
    red[1][threadIdx.x] = ssq;
    __syncthreads();
    if (threadIdx.x < 64) {
        const int which = threadIdx.x >> 5;   // 0: sum, 1: ssq
        const int cc = threadIdx.x & 31;
        float a = 0.f;
#pragma unroll
        for (int gg = 0; gg < 8; ++gg) a += red[which][(gg << 5) + cc];
        partials[(size_t)b * 64 + (which << 5) + cc] = a;
    }
}

// --- combine partials -> BN affine a,b -------------------------------------
__global__ __launch_bounds__(256) void k_finalize(
    const float* __restrict__ partials, int nblocks,
    const float* __restrict__ gamma, const float* __restrict__ beta,
    float* __restrict__ ab, float invE)
{
    __shared__ float acc[4][64];
    const int vtx = threadIdx.x & 63, chunk = threadIdx.x >> 6;
    float s = 0.f;
    for (int r = chunk; r < nblocks; r += 4) s += partials[(size_t)r * 64 + vtx];
    acc[chunk][vtx] = s;
    __syncthreads();
    if (threadIdx.x < 64) acc[0][vtx] = acc[0][vtx] + acc[1][vtx] + acc[2][vtx] + acc[3][vtx];
    __syncthreads();
    if (threadIdx.x < 32) {
        const int c = threadIdx.x;
        float mean = acc[0][c] * invE;
        float var  = acc[0][32 + c] * invE - mean * mean;
        float rstd = rsqrtf(var + 1e-5f);
        float a = gamma[c] * rstd;
        ab[c] = a; ab[32 + c] = beta[c] - mean * a;
    }
}

// --- per-bucket apply: LDS accumulate, coalesced store ---------------------
__global__ __launch_bounds__(256) void k_apply_b(
    const float* __restrict__ u, const float* __restrict__ v,
    const int* __restrict__ payload, const int* __restrict__ off_b,
    const int* __restrict__ cnt_b, const float* __restrict__ ab,
    float* __restrict__ out, int N)
{
    __shared__ float uL[BNODES * NCH];
    __shared__ float accL[BNODES * NCH];
    const int b = blockIdx.x;
    const int base = (b << BSH) * NCH;
    const int lim = N * NCH;
    for (int i = threadIdx.x; i < BNODES * NCH; i += 256) {
        const int gi = base + i;
        uL[i] = (gi < lim) ? u[gi] : 0.f;
        accL[i] = 0.f;
    }
    __syncthreads();

    const int off = off_b[b];
    const int cnt = cnt_b[b];
    const int g = threadIdx.x >> 5;
    const int c = threadIdx.x & 31;
    const float a_c = ab[c];
    const float b_c = ab[32 + c];
    for (int i = g; i < cnt; i += 8) {
        const int w = payload[off + i];
        const int t = w & 0x1FFFF;
        const int sl = w >> 17;
        const float y = uL[(sl << 5) + c] + v[(size_t)t * NCH + c];
        float z = fmaf(a_c, y, b_c);
        z = (z > 0.f) ? z : (__expf(z) - 1.0f);
        atomicAdd(&accL[(sl << 5) + c], z);   // ds_add_f32
    }
    __syncthreads();
    for (int i = threadIdx.x; i < BNODES * NCH; i += 256) {
        const int gi = base + i;
        if (gi < lim) out[gi] = accL[i];
    }
}

// ===========================================================================
// FALLBACK (round-1 proven path) — only if ws too small / N too large
// ===========================================================================
__global__ __launch_bounds__(256) void k_stats_hist(
    const float* __restrict__ x,
    const int* __restrict__ srci, const int* __restrict__ tgti,
    const float* __restrict__ W,
    float* __restrict__ partials, int E)
{
    float sum[NCH], ssq[NCH];
#pragma unroll
    for (int c = 0; c < NCH; ++c) { sum[c] = 0.f; ssq[c] = 0.f; }
    const int stride = gridDim.x * blockDim.x;
    for (int e = blockIdx.x * blockDim.x + threadIdx.x; e < E; e += stride) {
        const int s = srci[e], t = tgti[e];
        const float4* ps = (const float4*)(x + (size_t)s * NCH);
        const float4* pt = (const float4*)(x + (size_t)t * NCH);
        float xs[NCH], dx[NCH];
#pragma unroll
        for (int i = 0; i < 8; ++i) {
            float4 a = ps[i], bb = pt[i];
            xs[4*i+0] = a.x; xs[4*i+1] = a.y; xs[4*i+2] = a.z; xs[4*i+3] = a.w;
            dx[4*i+0] = bb.x - a.x; dx[4*i+1] = bb.y - a.y;
            dx[4*i+2] = bb.z - a.z; dx[4*i+3] = bb.w - a.w;
        }
#pragma unroll
        for (int c = 0; c < NCH; ++c) {
            const float* wr = W + c * 64;
            float y = 0.f;
#pragma unroll
            for (int k = 0; k < NCH; ++k) y = fmaf(wr[k], xs[k], y);
#pragma unroll
            for (int k = 0; k < NCH; ++k) y = fmaf(wr[32 + k], dx[k], y);
            sum[c] += y;
            ssq[c] = fmaf(y, y, ssq[c]);
        }
    }
#pragma unroll
    for (int c = 0; c < NCH; ++c) {
#pragma unroll
        for (int off = 32; off > 0; off >>= 1) {
            sum[c] += __shfl_down(sum[c], off);
            ssq[c] += __shfl_down(ssq[c], off);
        }
    }
    __shared__ float red[4][64];
    const int lane = threadIdx.x & 63, wave = threadIdx.x >> 6;
    if (lane == 0) {
#pragma unroll
        for (int c = 0; c < NCH; ++c) { red[wave][c] = sum[c]; red[wave][NCH+c] = ssq[c]; }
    }
    __syncthreads();
    if (threadIdx.x < 64)
        partials[(size_t)blockIdx.x * 64 + threadIdx.x] =
            red[0][threadIdx.x] + red[1][threadIdx.x] + red[2][threadIdx.x] + red[3][threadIdx.x];
}

__global__ __launch_bounds__(256) void k_apply_atomic(
    const float* __restrict__ x,
    const int* __restrict__ srci, const int* __restrict__ tgti,
    const float* __restrict__ W, const float* __restrict__ ab,
    float* __restrict__ out, int E)
{
    const int e = blockIdx.x * 256 + threadIdx.x;
    if (e >= E) return;
    const int s = srci[e], t = tgti[e];
    const float4* ps = (const float4*)(x + (size_t)s * NCH);
    const float4* pt = (const float4*)(x + (size_t)t * NCH);
    float xs[NCH], dx[NCH];
#pragma unroll
    for (int i = 0; i < 8; ++i) {
        float4 a = ps[i], bb = pt[i];
        xs[4*i+0] = a.x; xs[4*i+1] = a.y; xs[4*i+2] = a.z; xs[4*i+3] = a.w;
        dx[4*i+0] = bb.x - a.x; dx[4*i+1] = bb.y - a.y;
        dx[4*i+2] = bb.z - a.z; dx[4*i+3] = bb.w - a.w;
    }
    float* orow = out + (size_t)s * NCH;
#pragma unroll
    for (int c = 0; c < NCH; ++c) {
        const float* wr = W + c * 64;
        float y = 0.f;
#pragma unroll
        for (int k = 0; k < NCH; ++k) y = fmaf(wr[k], xs[k], y);
#pragma unroll
        for (int k = 0; k < NCH; ++k) y = fmaf(wr[32 + k], dx[k], y);
        float z = fmaf(ab[c], y, ab[32 + c]);
        z = (z > 0.f) ? z : (__expf(z) - 1.0f);
        atomicAdd(orow + c, z);
    }
}

// ===========================================================================
extern "C" void kernel_launch(void* const* d_in, const int* in_sizes, int n_in,
                              void* d_out, int out_size, void* d_ws, size_t ws_size,
                              hipStream_t stream)
{
    const float* x     = (const float*)d_in[0];
    const int*   ei    = (const int*)d_in[1];
    const float* W     = (const float*)d_in[2];
    const float* gamma = (const float*)d_in[3];
    const float* beta  = (const float*)d_in[4];
    const int E = in_sizes[1] / 2;
    const int N = in_sizes[0] / NCH;
    const int* srci = ei;
    const int* tgti = ei + E;

    const int NB = (N + BNODES - 1) >> BSH;

    // ws layout: u[N*32] v[N*32] | payload[E] cnt_b[NB] off_b[NB] cur_b[NB] |
    //            partials[NB*64] ab[64]
    size_t need = (size_t)(2 * N) * NCH * sizeof(float)
                + ((size_t)E + 3 * NB) * sizeof(int)
                + ((size_t)NB * 64 + 64) * sizeof(float);

    if (N <= 131072 && NB <= MAXNB && ws_size >= need) {
        float* u        = (float*)d_ws;
        float* v        = u + (size_t)N * NCH;
        int*   payload  = (int*)(v + (size_t)N * NCH);
        int*   cnt_b    = payload + E;
        int*   off_b    = cnt_b + NB;
        int*   cur_b    = off_b + NB;
        float* partials = (float*)(cur_b + NB);
        float* ab       = partials + (size_t)NB * 64;

        hipMemsetAsync(cnt_b, 0, (size_t)NB * sizeof(int), stream);
        k_uv<<<(N + 255) / 256, 256, 0, stream>>>(x, W, u, v, N);
        k_count<<<128, 256, 0, stream>>>(srci, cnt_b, E, NB);
        k_scan_b<<<1, 256, 0, stream>>>(cnt_b, off_b, cur_b, NB);
        k_bucket2<<<(E + 255) / 256, 256, 0, stream>>>(srci, tgti, cur_b, payload, E);
        k_stats_b<<<NB, 256, 0, stream>>>(u, v, payload, off_b, cnt_b, partials, N);
        k_finalize<<<1, 256, 0, stream>>>(partials, NB, gamma, beta, ab, 1.0f / (float)E);
        k_apply_b<<<NB, 256, 0, stream>>>(u, v, payload, off_b, cnt_b, ab, (float*)d_out, N);
    } else {
        const int SBf = 512;
        float* ab       = (float*)d_ws;
        float* partials = ab + 64;
        hipMemsetAsync(d_out, 0, (size_t)out_size * sizeof(float), stream);
        k_stats_hist<<<SBf, 256, 0, stream>>>(x, srci, tgti, W, partials, E);
        k_finalize<<<1, 256, 0, stream>>>(partials, SBf, gamma, beta, ab, 1.0f / (float)E);
        k_apply_atomic<<<(E + 255) / 256, 256, 0, stream>>>(x, srci, tgti, W, ab,
                                                            (float*)d_out, E);
    }
}

// Round 5
// 809.254 us; speedup vs baseline: 3.7938x; 1.0644x over previous
//
#include <hip/hip_runtime.h>
#include <math.h>

#define NCH 32
#define BSH 6                   // nodes per bucket = 64
#define BNODES (1 << BSH)
#define MAXNB 2048              // LDS histogram capacity (N <= 131072)
#define PCH 1024                // payload LDS staging chunk (ints)

// ===========================================================================
// FAST PATH:
//   u = (W1-W2) x, v = W2 x per node;  y_e = u[src] + v[tgt]
//   edges bucketed by src>>6 (payload packs src_local<<17 | tgt)
//   stats/apply: payload staged in LDS + 8x unrolled independent v-gathers
//   (round-4 post-mortem: non-pipelined chain was ~960 cyc/edge, VALU 7%)
// ===========================================================================

// --- per-node u, v ---------------------------------------------------------
__global__ __launch_bounds__(256) void k_uv(
    const float* __restrict__ x, const float* __restrict__ W,
    float* __restrict__ u, float* __restrict__ v, int N)
{
    const int n = blockIdx.x * 256 + threadIdx.x;
    if (n >= N) return;
    float xs[NCH];
    const float4* __restrict__ ps = (const float4*)(x + (size_t)n * NCH);
#pragma unroll
    for (int i = 0; i < 8; ++i) {
        float4 a = ps[i];
        xs[4*i+0] = a.x; xs[4*i+1] = a.y; xs[4*i+2] = a.z; xs[4*i+3] = a.w;
    }
    float4* __restrict__ pu = (float4*)(u + (size_t)n * NCH);
    float4* __restrict__ pv = (float4*)(v + (size_t)n * NCH);
#pragma unroll
    for (int i = 0; i < 8; ++i) {
        float r[8];
#pragma unroll
        for (int j = 0; j < 4; ++j) {
            const int c = 4*i + j;
            const float* __restrict__ wr = W + c * 64;   // uniform -> s_load
            float su = 0.f, sv = 0.f;
#pragma unroll
            for (int k = 0; k < NCH; ++k) {
                su = fmaf(wr[k] - wr[32 + k], xs[k], su);
                sv = fmaf(wr[32 + k], xs[k], sv);
            }
            r[j] = su; r[4 + j] = sv;
        }
        pu[i] = make_float4(r[0], r[1], r[2], r[3]);
        pv[i] = make_float4(r[4], r[5], r[6], r[7]);
    }
}

// --- bucket counts via LDS-privatized histogram ----------------------------
__global__ __launch_bounds__(256) void k_count(
    const int* __restrict__ srci, int* __restrict__ cnt_b, int E, int NB)
{
    __shared__ int h[MAXNB];
    for (int i = threadIdx.x; i < NB; i += 256) h[i] = 0;
    __syncthreads();
    const int stride = gridDim.x * 256;
    for (int e = blockIdx.x * 256 + threadIdx.x; e < E; e += stride)
        atomicAdd(&h[srci[e] >> BSH], 1);
    __syncthreads();
    for (int i = threadIdx.x; i < NB; i += 256)
        if (h[i]) atomicAdd(&cnt_b[i], h[i]);
}

// --- one-block exclusive scan over NB bucket counts ------------------------
__global__ __launch_bounds__(256) void k_scan_b(
    const int* __restrict__ cnt_b, int* __restrict__ off_b,
    int* __restrict__ cur_b, int NB)
{
    __shared__ int segsum[256];
    __shared__ int segoff[256];
    const int tid = threadIdx.x;
    const int per = (NB + 255) / 256;
    const int lo = tid * per;
    const int hi = min(lo + per, NB);
    int s = 0;
    for (int i = lo; i < hi; ++i) s += cnt_b[i];
    segsum[tid] = s;
    __syncthreads();
    if (tid == 0) {
        int a = 0;
        for (int i = 0; i < 256; ++i) { segoff[i] = a; a += segsum[i]; }
    }
    __syncthreads();
    int run = segoff[tid];
    for (int i = lo; i < hi; ++i) {
        off_b[i] = run;
        cur_b[i] = run;
        run += cnt_b[i];
    }
}

// --- scatter edges into buckets: payload = (src&63)<<17 | tgt --------------
__global__ __launch_bounds__(256) void k_bucket2(
    const int* __restrict__ srci, const int* __restrict__ tgti,
    int* __restrict__ cur_b, int* __restrict__ payload, int E)
{
    const int e = blockIdx.x * 256 + threadIdx.x;
    if (e >= E) return;
    const int s = srci[e];
    const int b = s >> BSH;
    const int pos = atomicAdd(&cur_b[b], 1);
    payload[pos] = ((s & (BNODES - 1)) << 17) | tgti[e];
}

// --- per-bucket stats: sum(y), sum(y^2), LDS-staged payload, 8x unroll -----
__global__ __launch_bounds__(256) void k_stats_b(
    const float* __restrict__ u, const float* __restrict__ v,
    const int* __restrict__ payload, const int* __restrict__ off_b,
    const int* __restrict__ cnt_b,
    float* __restrict__ partials, int N)
{
    __shared__ float uL[BNODES * NCH];
    __shared__ int pL[PCH];
    __shared__ float red[2][256];
    const int b = blockIdx.x;
    const int base = (b << BSH) * NCH;
    const int lim = N * NCH;
    for (int i = threadIdx.x; i < BNODES * NCH; i += 256) {
        const int gi = base + i;
        uL[i] = (gi < lim) ? u[gi] : 0.f;
    }

    const int off = off_b[b];
    const int cnt = cnt_b[b];
    const int g = threadIdx.x >> 5;     // edge sub-lane 0..7
    const int c = threadIdx.x & 31;     // channel
    float sum = 0.f, ssq = 0.f;

    for (int chunk = 0; chunk < cnt; chunk += PCH) {
        const int m = min(PCH, cnt - chunk);
        __syncthreads();
        for (int i = threadIdx.x; i < m; i += 256) pL[i] = payload[off + chunk + i];
        __syncthreads();
        int i = g;
        for (; i + 64 <= m; i += 64) {          // batch of 8 edges per group
            int w[8]; float vv[8];
#pragma unroll
            for (int k = 0; k < 8; ++k) w[k] = pL[i + 8*k];
#pragma unroll
            for (int k = 0; k < 8; ++k)
                vv[k] = v[(size_t)(w[k] & 0x1FFFF) * NCH + c];   // 8 indep gathers
#pragma unroll
            for (int k = 0; k < 8; ++k) {
                const float y = uL[((w[k] >> 17) << 5) + c] + vv[k];
                sum += y;
                ssq = fmaf(y, y, ssq);
            }
        }
        for (; i < m; i += 8) {                 // tail
            const int w = pL[i];
            const float y = uL[((w >> 17) << 5) + c]
                          + v[(size_t)(w & 0x1FFFF) * NCH + c];
            sum += y;
            ssq = fmaf(y, y, ssq);
        }
    }

    red[0][threadIdx.x] = sum;
    red[1][threadIdx.x] = ssq;
    __syncthreads();
    if (threadIdx.x < 64) {
        const int which = threadIdx.x >> 5;   // 0: sum, 1: ssq
        const int cc = threadIdx.x & 31;
        float a = 0.f;
#pragma unroll
        for (int gg = 0; gg < 8; ++gg) a += red[which][(gg << 5) + cc];
        partials[(size_t)b * 64 + (which << 5) + cc] = a;
    }
}

// --- combine partials -> BN affine a,b -------------------------------------
__global__ __launch_bounds__(256) void k_finalize(
    const float* __restrict__ partials, int nblocks,
    const float* __restrict__ gamma, const float* __restrict__ beta,
    float* __restrict__ ab, float invE)
{
    __shared__ float acc[4][64];
    const int vtx = threadIdx.x & 63, chunk = threadIdx.x >> 6;
    float s = 0.f;
    for (int r = chunk; r < nblocks; r += 4) s += partials[(size_t)r * 64 + vtx];
    acc[chunk][vtx] = s;
    __syncthreads();
    if (threadIdx.x < 64) acc[0][vtx] = acc[0][vtx] + acc[1][vtx] + acc[2][vtx] + acc[3][vtx];
    __syncthreads();
    if (threadIdx.x < 32) {
        const int c = threadIdx.x;
        float mean = acc[0][c] * invE;
        float var  = acc[0][32 + c] * invE - mean * mean;
        float rstd = rsqrtf(var + 1e-5f);
        float a = gamma[c] * rstd;
        ab[c] = a; ab[32 + c] = beta[c] - mean * a;
    }
}

// --- per-bucket apply: LDS-staged payload, 8x unroll, LDS accumulate -------
__global__ __launch_bounds__(256) void k_apply_b(
    const float* __restrict__ u, const float* __restrict__ v,
    const int* __restrict__ payload, const int* __restrict__ off_b,
    const int* __restrict__ cnt_b, const float* __restrict__ ab,
    float* __restrict__ out, int N)
{
    __shared__ float uL[BNODES * NCH];
    __shared__ float accL[BNODES * NCH];
    __shared__ int pL[PCH];
    const int b = blockIdx.x;
    const int base = (b << BSH) * NCH;
    const int lim = N * NCH;
    for (int i = threadIdx.x; i < BNODES * NCH; i += 256) {
        const int gi = base + i;
        uL[i] = (gi < lim) ? u[gi] : 0.f;
        accL[i] = 0.f;
    }

    const int off = off_b[b];
    const int cnt = cnt_b[b];
    const int g = threadIdx.x >> 5;
    const int c = threadIdx.x & 31;
    const float a_c = ab[c];
    const float b_c = ab[32 + c];

    for (int chunk = 0; chunk < cnt; chunk += PCH) {
        const int m = min(PCH, cnt - chunk);
        __syncthreads();
        for (int i = threadIdx.x; i < m; i += 256) pL[i] = payload[off + chunk + i];
        __syncthreads();
        int i = g;
        for (; i + 64 <= m; i += 64) {
            int w[8]; float vv[8];
#pragma unroll
            for (int k = 0; k < 8; ++k) w[k] = pL[i + 8*k];
#pragma unroll
            for (int k = 0; k < 8; ++k)
                vv[k] = v[(size_t)(w[k] & 0x1FFFF) * NCH + c];
#pragma unroll
            for (int k = 0; k < 8; ++k) {
                const int sl = w[k] >> 17;
                const float y = uL[(sl << 5) + c] + vv[k];
                float z = fmaf(a_c, y, b_c);
                z = (z > 0.f) ? z : (__expf(z) - 1.0f);
                atomicAdd(&accL[(sl << 5) + c], z);   // ds_add_f32
            }
        }
        for (; i < m; i += 8) {
            const int w = pL[i];
            const int sl = w >> 17;
            const float y = uL[(sl << 5) + c] + v[(size_t)(w & 0x1FFFF) * NCH + c];
            float z = fmaf(a_c, y, b_c);
            z = (z > 0.f) ? z : (__expf(z) - 1.0f);
            atomicAdd(&accL[(sl << 5) + c], z);
        }
    }
    __syncthreads();
    for (int i = threadIdx.x; i < BNODES * NCH; i += 256) {
        const int gi = base + i;
        if (gi < lim) out[gi] = accL[i];
    }
}

// ===========================================================================
// FALLBACK (round-1 proven path) — only if ws too small / N too large
// ===========================================================================
__global__ __launch_bounds__(256) void k_stats_hist(
    const float* __restrict__ x,
    const int* __restrict__ srci, const int* __restrict__ tgti,
    const float* __restrict__ W,
    float* __restrict__ partials, int E)
{
    float sum[NCH], ssq[NCH];
#pragma unroll
    for (int c = 0; c < NCH; ++c) { sum[c] = 0.f; ssq[c] = 0.f; }
    const int stride = gridDim.x * blockDim.x;
    for (int e = blockIdx.x * blockDim.x + threadIdx.x; e < E; e += stride) {
        const int s = srci[e], t = tgti[e];
        const float4* ps = (const float4*)(x + (size_t)s * NCH);
        const float4* pt = (const float4*)(x + (size_t)t * NCH);
        float xs[NCH], dx[NCH];
#pragma unroll
        for (int i = 0; i < 8; ++i) {
            float4 a = ps[i], bb = pt[i];
            xs[4*i+0] = a.x; xs[4*i+1] = a.y; xs[4*i+2] = a.z; xs[4*i+3] = a.w;
            dx[4*i+0] = bb.x - a.x; dx[4*i+1] = bb.y - a.y;
            dx[4*i+2] = bb.z - a.z; dx[4*i+3] = bb.w - a.w;
        }
#pragma unroll
        for (int c = 0; c < NCH; ++c) {
            const float* wr = W + c * 64;
            float y = 0.f;
#pragma unroll
            for (int k = 0; k < NCH; ++k) y = fmaf(wr[k], xs[k], y);
#pragma unroll
            for (int k = 0; k < NCH; ++k) y = fmaf(wr[32 + k], dx[k], y);
            sum[c] += y;
            ssq[c] = fmaf(y, y, ssq[c]);
        }
    }
#pragma unroll
    for (int c = 0; c < NCH; ++c) {
#pragma unroll
        for (int off = 32; off > 0; off >>= 1) {
            sum[c] += __shfl_down(sum[c], off);
            ssq[c] += __shfl_down(ssq[c], off);
        }
    }
    __shared__ float red[4][64];
    const int lane = threadIdx.x & 63, wave = threadIdx.x >> 6;
    if (lane == 0) {
#pragma unroll
        for (int c = 0; c < NCH; ++c) { red[wave][c] = sum[c]; red[wave][NCH+c] = ssq[c]; }
    }
    __syncthreads();
    if (threadIdx.x < 64)
        partials[(size_t)blockIdx.x * 64 + threadIdx.x] =
            red[0][threadIdx.x] + red[1][threadIdx.x] + red[2][threadIdx.x] + red[3][threadIdx.x];
}

__global__ __launch_bounds__(256) void k_apply_atomic(
    const float* __restrict__ x,
    const int* __restrict__ srci, const int* __restrict__ tgti,
    const float* __restrict__ W, const float* __restrict__ ab,
    float* __restrict__ out, int E)
{
    const int e = blockIdx.x * 256 + threadIdx.x;
    if (e >= E) return;
    const int s = srci[e], t = tgti[e];
    const float4* ps = (const float4*)(x + (size_t)s * NCH);
    const float4* pt = (const float4*)(x + (size_t)t * NCH);
    float xs[NCH], dx[NCH];
#pragma unroll
    for (int i = 0; i < 8; ++i) {
        float4 a = ps[i], bb = pt[i];
        xs[4*i+0] = a.x; xs[4*i+1] = a.y; xs[4*i+2] = a.z; xs[4*i+3] = a.w;
        dx[4*i+0] = bb.x - a.x; dx[4*i+1] = bb.y - a.y;
        dx[4*i+2] = bb.z - a.z; dx[4*i+3] = bb.w - a.w;
    }
    float* orow = out + (size_t)s * NCH;
#pragma unroll
    for (int c = 0; c < NCH; ++c) {
        const float* wr = W + c * 64;
        float y = 0.f;
#pragma unroll
        for (int k = 0; k < NCH; ++k) y = fmaf(wr[k], xs[k], y);
#pragma unroll
        for (int k = 0; k < NCH; ++k) y = fmaf(wr[32 + k], dx[k], y);
        float z = fmaf(ab[c], y, ab[32 + c]);
        z = (z > 0.f) ? z : (__expf(z) - 1.0f);
        atomicAdd(orow + c, z);
    }
}

// ===========================================================================
extern "C" void kernel_launch(void* const* d_in, const int* in_sizes, int n_in,
                              void* d_out, int out_size, void* d_ws, size_t ws_size,
                              hipStream_t stream)
{
    const float* x     = (const float*)d_in[0];
    const int*   ei    = (const int*)d_in[1];
    const float* W     = (const float*)d_in[2];
    const float* gamma = (const float*)d_in[3];
    const float* beta  = (const float*)d_in[4];
    const int E = in_sizes[1] / 2;
    const int N = in_sizes[0] / NCH;
    const int* srci = ei;
    const int* tgti = ei + E;

    const int NB = (N + BNODES - 1) >> BSH;

    // ws layout: u[N*32] v[N*32] | payload[E] cnt_b[NB] off_b[NB] cur_b[NB] |
    //            partials[NB*64] ab[64]
    size_t need = (size_t)(2 * N) * NCH * sizeof(float)
                + ((size_t)E + 3 * NB) * sizeof(int)
                + ((size_t)NB * 64 + 64) * sizeof(float);

    if (N <= 131072 && NB <= MAXNB && ws_size >= need) {
        float* u        = (float*)d_ws;
        float* v        = u + (size_t)N * NCH;
        int*   payload  = (int*)(v + (size_t)N * NCH);
        int*   cnt_b    = payload + E;
        int*   off_b    = cnt_b + NB;
        int*   cur_b    = off_b + NB;
        float* partials = (float*)(cur_b + NB);
        float* ab       = partials + (size_t)NB * 64;

        hipMemsetAsync(cnt_b, 0, (size_t)NB * sizeof(int), stream);
        k_uv<<<(N + 255) / 256, 256, 0, stream>>>(x, W, u, v, N);
        k_count<<<128, 256, 0, stream>>>(srci, cnt_b, E, NB);
        k_scan_b<<<1, 256, 0, stream>>>(cnt_b, off_b, cur_b, NB);
        k_bucket2<<<(E + 255) / 256, 256, 0, stream>>>(srci, tgti, cur_b, payload, E);
        k_stats_b<<<NB, 256, 0, stream>>>(u, v, payload, off_b, cnt_b, partials, N);
        k_finalize<<<1, 256, 0, stream>>>(partials, NB, gamma, beta, ab, 1.0f / (float)E);
        k_apply_b<<<NB, 256, 0, stream>>>(u, v, payload, off_b, cnt_b, ab, (float*)d_out, N);
    } else {
        const int SBf = 512;
        float* ab       = (float*)d_ws;
        float* partials = ab + 64;
        hipMemsetAsync(d_out, 0, (size_t)out_size * sizeof(float), stream);
        k_stats_hist<<<SBf, 256, 0, stream>>>(x, srci, tgti, W, partials, E);
        k_finalize<<<1, 256, 0, stream>>>(partials, SBf, gamma, beta, ab, 1.0f / (float)E);
        k_apply_atomic<<<(E + 255) / 256, 256, 0, stream>>>(x, srci, tgti, W, ab,
                                                            (float*)d_out, E);
    }
}